// Round 8
// baseline (497.035 us; speedup 1.0000x reference)
//
#include <hip/hip_runtime.h>
#include <cmath>

#define B_ 4
#define T_ 8192
#define C_ 256
#define E_ 8
#define M_ (B_*T_)

typedef __bf16 bf16x8 __attribute__((ext_vector_type(8)));
typedef float  f32x4  __attribute__((ext_vector_type(4)));

typedef const __attribute__((address_space(1))) unsigned int* gas_t;
typedef __attribute__((address_space(3))) unsigned int* las_t;

static __device__ __forceinline__ unsigned short f2bf(float f) {
    union { float fv; unsigned u; } v; v.fv = f;
    unsigned r = v.u + 0x7FFFu + ((v.u >> 16) & 1u);
    return (unsigned short)(r >> 16);
}

// Abramowitz-Stegun 7.1.26: |err| <= 1.5e-7
static __device__ __forceinline__ float fast_erf(float x) {
    float ax = fabsf(x);
    float t = __builtin_amdgcn_rcpf(1.0f + 0.3275911f * ax);
    float p = ((((1.061405429f * t - 1.453152027f) * t) + 1.421413741f) * t - 0.284496736f) * t + 0.254829592f;
    float y = 1.0f - p * t * __expf(-ax * ax);
    return copysignf(y, x);
}

static __device__ __forceinline__ float gelu_f(float x) {
    return 0.5f * x * (1.0f + fast_erf(x * 0.7071067811865476f));
}

static __device__ __forceinline__ f32x4 mfma16(bf16x8 a, bf16x8 b, f32x4 c) {
    return __builtin_amdgcn_mfma_f32_16x16x32_bf16(a, b, c, 0, 0, 0);
}

// stage one 16KB weight chunk [256 cols][32 k] bf16 into LDS, bank-swizzled.
// LDS 16B-slot s holds (col = s>>2, kseg = (s&3) ^ ((col>>1)&3)).
// Read side: slot = (col<<2) + (khi ^ ((col>>1)&3)) -> for a quarter-wave
// (16 rlo lanes, col = base+rlo) slot%8 covers each bank-group exactly twice
// (2-way = free). LDS dest linear (global_load_lds constraint); src pre-swizzled.
static __device__ __forceinline__ void stage_swz(const unsigned short* __restrict__ src,
                                                 unsigned short* lds_base, int tid) {
#pragma unroll
    for (int i = 0; i < 4; i++) {
        int s = i * 256 + tid;
        int col = s >> 2;
        int kseg = (s & 3) ^ ((col >> 1) & 3);
        const unsigned short* gp = src + (col << 8) + (kseg << 3);
        unsigned short* lp = lds_base + ((i * 256 + (tid & ~63)) << 3);
        __builtin_amdgcn_global_load_lds((gas_t)(const void*)gp, (las_t)(void*)lp, 16, 0, 0);
    }
}

// ---------------- prep kernels ----------------

// w1t[e][c][k] = W1[e][k][c], k in [0,256)  (tiled coalesced transpose)
__global__ void k_w1t(const float* __restrict__ W1, unsigned short* __restrict__ w1t) {
    __shared__ float tile[64][65];
    int e = blockIdx.x >> 4, kt = (blockIdx.x >> 2) & 3, ct = blockIdx.x & 3;
    int k0 = kt << 6, c0 = ct << 6;
    const float* src = W1 + ((size_t)e << 18) + ((size_t)k0 << 8) + c0;
    int r = threadIdx.x >> 6, col = threadIdx.x & 63;
#pragma unroll
    for (int i = 0; i < 16; i++)
        tile[r + i * 4][col] = src[(size_t)(r + i * 4) * 256 + col];
    __syncthreads();
    unsigned short* dst = w1t + (e << 16) + (c0 << 8) + k0;
#pragma unroll
    for (int i = 0; i < 16; i++)
        dst[(r + i * 4) * 256 + col] = f2bf(tile[col][r + i * 4]);
}

// w2t[e][f][c] = W2[e][c][f]
__global__ void k_w2t(const float* __restrict__ W2, unsigned short* __restrict__ w2t) {
    __shared__ float tile[64][65];
    int e = blockIdx.x >> 4, ct = (blockIdx.x >> 2) & 3, ft = blockIdx.x & 3;
    int c0 = ct << 6, f0 = ft << 6;
    const float* src = W2 + ((size_t)e << 16) + ((size_t)c0 << 8) + f0;
    int r = threadIdx.x >> 6, col = threadIdx.x & 63;
#pragma unroll
    for (int i = 0; i < 16; i++)
        tile[r + i * 4][col] = src[(size_t)(r + i * 4) * 256 + col];
    __syncthreads();
    unsigned short* dst = w2t + (e << 16) + (f0 << 8) + c0;
#pragma unroll
    for (int i = 0; i < 16; i++)
        dst[(r + i * 4) * 256 + col] = f2bf(tile[col][r + i * 4]);
}

// v2[e][c] = sum_f W2[e,c,f]*We[e,f];
// bc2[e] = -beta*( sum_f b2[e,f]*We[e,f] + be[e] + prior[e] );  bbeta[0] = beta
__global__ void k_v2(const float* __restrict__ W2, const float* __restrict__ We,
                     const float* __restrict__ b2, const float* __restrict__ be,
                     const float* __restrict__ log_beta, const float* __restrict__ prior,
                     float* __restrict__ v2, float* __restrict__ bc2, float* __restrict__ bbeta) {
    __shared__ float sm[4];
    int e = blockIdx.x >> 8, c = blockIdx.x & 255, f = threadIdx.x;
    float wef = We[(e << 8) + f];
    float v = W2[((((e << 8) + c) << 8)) + f] * wef;
#pragma unroll
    for (int m = 32; m >= 1; m >>= 1) v += __shfl_xor(v, m);
    if ((f & 63) == 0) sm[f >> 6] = v;
    __syncthreads();
    if (f == 0) v2[(e << 8) + c] = sm[0] + sm[1] + sm[2] + sm[3];
    if (c == 0) {
        __syncthreads();
        float u = b2[(e << 8) + f] * wef;
#pragma unroll
        for (int m = 32; m >= 1; m >>= 1) u += __shfl_xor(u, m);
        if ((f & 63) == 0) sm[f >> 6] = u;
        __syncthreads();
        if (f == 0) {
            float beta = __expf(log_beta[0]);
            float c2e = sm[0] + sm[1] + sm[2] + sm[3] + be[e];
            bc2[e] = -beta * (c2e + prior[e]);
            if (e == 0) bbeta[0] = beta;
        }
    }
}

// ---------------- LN + masked stats (+ x -> bf16 conversion fused) ----------------

__global__ void k_stats(const float* __restrict__ x, const int* __restrict__ mask,
                        const float* __restrict__ lnw, const float* __restrict__ lnb,
                        float* __restrict__ S1, float* __restrict__ S2, float* __restrict__ ncnt,
                        unsigned short* __restrict__ xb) {
    int b = blockIdx.x >> 6;
    int chunk = blockIdx.x & 63;
    int wid = threadIdx.x >> 6, lane = threadIdx.x & 63;
    int c0 = lane << 2;
    float4 w4 = *reinterpret_cast<const float4*>(lnw + c0);
    float4 b4 = *reinterpret_cast<const float4*>(lnb + c0);
    float a1[4] = {0,0,0,0}, a2[4] = {0,0,0,0};
    int cnt = 0;
    int tbase = chunk * 128;
    for (int r = wid; r < 128; r += 4) {
        int row = b * T_ + tbase + r;
        float4 xv = *reinterpret_cast<const float4*>(x + (size_t)row * C_ + c0);
        ushort4 o;
        o.x = f2bf(xv.x); o.y = f2bf(xv.y); o.z = f2bf(xv.z); o.w = f2bf(xv.w);
        *reinterpret_cast<ushort4*>(xb + (size_t)row * C_ + c0) = o;
        float s1 = xv.x + xv.y + xv.z + xv.w;
        float s2 = xv.x*xv.x + xv.y*xv.y + xv.z*xv.z + xv.w*xv.w;
#pragma unroll
        for (int m = 1; m < 64; m <<= 1) { s1 += __shfl_xor(s1, m); s2 += __shfl_xor(s2, m); }
        if (mask[row]) {
            float mu = s1 * (1.f / C_);
            float var = s2 * (1.f / C_) - mu * mu;
            float rs = rsqrtf(var + 1e-5f);
            float hv;
            hv = (xv.x - mu) * rs * w4.x + b4.x; a1[0] += hv; a2[0] += hv * hv;
            hv = (xv.y - mu) * rs * w4.y + b4.y; a1[1] += hv; a2[1] += hv * hv;
            hv = (xv.z - mu) * rs * w4.z + b4.z; a1[2] += hv; a2[2] += hv * hv;
            hv = (xv.w - mu) * rs * w4.w + b4.w; a1[3] += hv; a2[3] += hv * hv;
            cnt++;
        }
    }
    __shared__ float red[4][256];
    __shared__ int rc[4];
#pragma unroll
    for (int j = 0; j < 4; j++) red[wid][c0 + j] = a1[j];
    if (lane == 0) rc[wid] = cnt;
    __syncthreads();
    int ch = threadIdx.x;
    float s = red[0][ch] + red[1][ch] + red[2][ch] + red[3][ch];
    atomicAdd(&S1[(b << 8) + ch], s);
    if (threadIdx.x == 0) atomicAdd(&ncnt[b], (float)(rc[0] + rc[1] + rc[2] + rc[3]));
    __syncthreads();
#pragma unroll
    for (int j = 0; j < 4; j++) red[wid][c0 + j] = a2[j];
    __syncthreads();
    s = red[0][ch] + red[1][ch] + red[2][ch] + red[3][ch];
    atomicAdd(&S2[(b << 8) + ch], s);
}

__global__ void k_stats_fin(const float* __restrict__ S1, const float* __restrict__ S2,
                            const float* __restrict__ ncnt, float* __restrict__ stats) {
    int b = blockIdx.x, c = threadIdx.x;
    float n = fmaxf(ncnt[b], 1.f);
    float mean = S1[(b << 8) + c] / n;
    float var_b = fmaxf(S2[(b << 8) + c] / n - mean * mean, 0.f);
    float var_u = (n > 1.f) ? (var_b * (n / fmaxf(n - 1.f, 1e-9f))) : var_b;
    float std_u = fmaxf(sqrtf(var_u), 1e-9f);
    stats[b * 768 + 0 * 256 + c] = mean;
    stats[b * 768 + 1 * 256 + c] = std_u;
    stats[b * 768 + 2 * 256 + c] = var_u;
}

__global__ void k_bias(const float* __restrict__ W1, const float* __restrict__ b1,
                       const float* __restrict__ stats, float* __restrict__ bias) {
    int b = blockIdx.x >> 3, e = blockIdx.x & 7, c = threadIdx.x;
    __shared__ float sm[768];
    for (int i = threadIdx.x; i < 768; i += 256) sm[i] = stats[b * 768 + i];
    __syncthreads();
    const float* w = W1 + (size_t)e * 1024 * 256;
    float acc = b1[(e << 8) + c];
#pragma unroll 4
    for (int j = 0; j < 256; j++) {
        acc += sm[j]       * w[(256 + j) * 256 + c];
        acc += sm[256 + j] * w[(512 + j) * 256 + c];
        acc += sm[512 + j] * w[(768 + j) * 256 + c];
    }
    bias[((b << 3) + e) * 256 + c] = acc;
}

// ---------------- fused: GEMM1 + gelu + energy + online softmax + GEMM2 ----------------
// Round-7 skeleton with wave N-SPLIT: 512 blocks x 256 thr, 64 rows/block;
// each wave computes ALL 64 rows x its 64-col quarter (4 mt x 4 nt 16x16 tiles).
// B LDS reads drop 4x (16KB/block/phase). GEMM1 A from xb (L1-hot, per phase);
// GEMM2 A from block-shared h1s. Softmax state held by threads 0..63 (row=tid),
// merge factors exchanged via LDS once per expert.

__global__ __launch_bounds__(256, 2) void k_fused(
    const unsigned short* __restrict__ xb, const unsigned short* __restrict__ w1t,
    const unsigned short* __restrict__ w2t, const float* __restrict__ bias,
    const float* __restrict__ v2, const float* __restrict__ bc2,
    const float* __restrict__ bbeta, const int* __restrict__ mask,
    const float* __restrict__ b2, float* __restrict__ out) {
    __shared__ unsigned short bstage[2][8192];  // 2 x 16KB swizzled weight chunks
    __shared__ unsigned short h1s[16384];       // [64][256] bf16, row-XOR swizzle
    __shared__ float scr[256];                  // 4 waves x 64 rows energy partials
    __shared__ float rs_[64], us_[64], sinv_[64];

    int row0 = blockIdx.x << 6;
    int b = row0 >> 13;
    int tid = threadIdx.x;
    int wid = tid >> 6, lane = tid & 63;
    int rlo = lane & 15, khi = lane >> 4;
    int nwo = wid << 6;                         // wave's 64-col window

    // softmax state: thread t<64 owns row t
    int mreg = 0; float m_run = -3.0e38f, s_run = 0.f, beta = 0.f;
    float bc2r[8];
    if (tid < 64) {
        mreg = mask[row0 + tid];
        beta = bbeta[0];
#pragma unroll
        for (int e = 0; e < 8; e++) bc2r[e] = bc2[e];
    }

    f32x4 acc2[4][4], acc1[4][4];
#pragma unroll
    for (int mt = 0; mt < 4; mt++)
#pragma unroll
        for (int nt = 0; nt < 4; nt++)
#pragma unroll
            for (int i = 0; i < 4; i++) acc2[mt][nt][i] = 0.f;

    stage_swz(w1t, &bstage[0][0], tid);
    __syncthreads();

    int pc = 0;
    for (int e = 0; e < E_; e++) {
        // ---- GEMM1: acc1 = x @ W1x + bias_fold (8 staged phases) ----
        const float* bre = bias + (((b << 3) + e) << 8);
#pragma unroll
        for (int nt = 0; nt < 4; nt++) {
            float bv = bre[nwo + (nt << 4) + rlo];
#pragma unroll
            for (int mt = 0; mt < 4; mt++)
#pragma unroll
                for (int i = 0; i < 4; i++) acc1[mt][nt][i] = bv;
        }
#pragma unroll
        for (int kk = 0; kk < 8; kk++) {
            int nc = pc + 1;
            if (nc < 128) {
                const unsigned short* nsrc = (((nc >> 3) & 1) ? w2t : w1t) + ((nc >> 4) << 16) + ((nc & 7) << 5);
                stage_swz(nsrc, &bstage[nc & 1][0], tid);
            }
            // A: 4 m-tiles from xb (L1-hot block slice)
            bf16x8 a[4];
#pragma unroll
            for (int mt = 0; mt < 4; mt++)
                a[mt] = *reinterpret_cast<const bf16x8*>(
                    xb + (size_t)(row0 + (mt << 4) + rlo) * C_ + (kk << 5) + (khi << 3));
            const unsigned short* bs = &bstage[pc & 1][0];
#pragma unroll
            for (int nt = 0; nt < 4; nt++) {
                int col = nwo + (nt << 4) + rlo;
                int slot = (col << 2) + (khi ^ ((col >> 1) & 3));
                bf16x8 bf = *reinterpret_cast<const bf16x8*>(bs + (slot << 3));
#pragma unroll
                for (int mt = 0; mt < 4; mt++)
                    acc1[mt][nt] = mfma16(a[mt], bf, acc1[mt][nt]);
            }
            __syncthreads();
            pc++;
        }
        // ---- gelu (in place) + energy partials (this wave's 64 cols) ----
        float v2v[4];
#pragma unroll
        for (int nt = 0; nt < 4; nt++) v2v[nt] = v2[(e << 8) + nwo + (nt << 4) + rlo];
        float epr[4][4];
#pragma unroll
        for (int mt = 0; mt < 4; mt++)
#pragma unroll
            for (int i = 0; i < 4; i++) {
                float s = 0.f;
#pragma unroll
                for (int nt = 0; nt < 4; nt++) {
                    float g = gelu_f(acc1[mt][nt][i]);
                    acc1[mt][nt][i] = g;
                    s += g * v2v[nt];
                }
                epr[mt][i] = s;
            }
#pragma unroll
        for (int m = 1; m < 16; m <<= 1)
#pragma unroll
            for (int mt = 0; mt < 4; mt++)
#pragma unroll
                for (int i = 0; i < 4; i++) epr[mt][i] += __shfl_xor(epr[mt][i], m);
        // ---- unscaled gelu(h1) -> block-shared LDS (row-XOR swizzle) ----
#pragma unroll
        for (int mt = 0; mt < 4; mt++)
#pragma unroll
            for (int i = 0; i < 4; i++) {
                int rowl = (mt << 4) + (khi << 2) + i;
#pragma unroll
                for (int nt = 0; nt < 4; nt++) {
                    int col = nwo + (nt << 4) + rlo;
                    int byteoff = ((rowl << 9) + (col << 1)) ^ ((rowl & 7) << 4);
                    *reinterpret_cast<unsigned short*>(reinterpret_cast<char*>(h1s) + byteoff)
                        = f2bf(acc1[mt][nt][i]);
                }
                if (rlo == 0) scr[(wid << 6) + rowl] = epr[mt][i];
            }
        __syncthreads();                        // h1s + scr visible
        // ---- online softmax update (threads 0..63, row = tid) ----
        if (tid < 64) {
            float en = scr[tid] + scr[64 + tid] + scr[128 + tid] + scr[192 + tid];
            float nb = -beta * en + bc2r[e];
            float mn = fmaxf(m_run, nb);
            float rr = __expf(m_run - mn);
            float uu = __expf(nb - mn);
            s_run = s_run * rr + uu;
            m_run = mn;
            rs_[tid] = rr; us_[tid] = uu;
        }
        __syncthreads();                        // rs_/us_ visible
        // ---- GEMM2: acc1 = gelu_h1 @ W2 + b2 (8 staged phases) ----
#pragma unroll
        for (int nt = 0; nt < 4; nt++) {
            float bv = b2[(e << 8) + nwo + (nt << 4) + rlo];
#pragma unroll
            for (int mt = 0; mt < 4; mt++)
#pragma unroll
                for (int i = 0; i < 4; i++) acc1[mt][nt][i] = bv;
        }
#pragma unroll
        for (int kk = 0; kk < 8; kk++) {
            int nc = pc + 1;
            if (nc < 128) {
                const unsigned short* nsrc = (((nc >> 3) & 1) ? w2t : w1t) + ((nc >> 4) << 16) + ((nc & 7) << 5);
                stage_swz(nsrc, &bstage[nc & 1][0], tid);
            }
            // A: 4 m-tiles from h1s
            bf16x8 a2[4];
#pragma unroll
            for (int mt = 0; mt < 4; mt++) {
                int rowA = (mt << 4) + rlo;
                int byteoff = ((rowA << 9) + (kk << 6) + (khi << 4)) ^ ((rowA & 7) << 4);
                a2[mt] = *reinterpret_cast<const bf16x8*>(reinterpret_cast<const char*>(h1s) + byteoff);
            }
            const unsigned short* bs = &bstage[pc & 1][0];
#pragma unroll
            for (int nt = 0; nt < 4; nt++) {
                int col = nwo + (nt << 4) + rlo;
                int slot = (col << 2) + (khi ^ ((col >> 1) & 3));
                bf16x8 bf = *reinterpret_cast<const bf16x8*>(bs + (slot << 3));
#pragma unroll
                for (int mt = 0; mt < 4; mt++)
                    acc1[mt][nt] = mfma16(a2[mt], bf, acc1[mt][nt]);
            }
            __syncthreads();
            pc++;
        }
        // ---- merge: acc2 = acc2*rr + uu*acc1 (rr/uu per row from LDS) ----
#pragma unroll
        for (int mt = 0; mt < 4; mt++)
#pragma unroll
            for (int i = 0; i < 4; i++) {
                int rowl = (mt << 4) + (khi << 2) + i;
                float rr = rs_[rowl];
                float uu = us_[rowl];
#pragma unroll
                for (int nt = 0; nt < 4; nt++)
                    acc2[mt][nt][i] = acc2[mt][nt][i] * rr + uu * acc1[mt][nt][i];
            }
    }
    // ---- epilogue: divide by partition sum, mask ----
    if (tid < 64) sinv_[tid] = mreg ? (1.0f / s_run) : 0.f;
    __syncthreads();
#pragma unroll
    for (int mt = 0; mt < 4; mt++)
#pragma unroll
        for (int i = 0; i < 4; i++) {
            int rowl = (mt << 4) + (khi << 2) + i;
            float si = sinv_[rowl];
            float* orow = out + (size_t)(row0 + rowl) * C_;
#pragma unroll
            for (int nt = 0; nt < 4; nt++)
                orow[nwo + (nt << 4) + rlo] = acc2[mt][nt][i] * si;
        }
}

// ---------------- launch ----------------

extern "C" void kernel_launch(void* const* d_in, const int* in_sizes, int n_in,
                              void* d_out, int out_size, void* d_ws, size_t ws_size,
                              hipStream_t stream) {
    (void)in_sizes; (void)n_in; (void)out_size; (void)ws_size;
    const float* x        = (const float*)d_in[0];
    const int*   mask     = (const int*)d_in[1];
    const float* lnw      = (const float*)d_in[2];
    const float* lnb      = (const float*)d_in[3];
    const float* W1       = (const float*)d_in[4];
    const float* b1       = (const float*)d_in[5];
    const float* W2       = (const float*)d_in[6];
    const float* b2       = (const float*)d_in[7];
    const float* We       = (const float*)d_in[8];
    const float* be       = (const float*)d_in[9];
    const float* log_beta = (const float*)d_in[10];
    const float* prior    = (const float*)d_in[11];
    float* out = (float*)d_out;
    char* ws = (char*)d_ws;

    constexpr size_t OFF_XB    = 0;                       // 16 MB
    constexpr size_t OFF_W1T   = 16777216;                // 1 MB
    constexpr size_t OFF_W2T   = 17825792;                // 1 MB
    constexpr size_t OFF_V2    = 18874368;                // 8 KB
    constexpr size_t OFF_BC2   = 18882560;                // 32 B
    constexpr size_t OFF_S1    = 18882592;                // 4 KB
    constexpr size_t OFF_S2    = 18886688;                // 4 KB
    constexpr size_t OFF_N     = 18890784;                // 16 B
    constexpr size_t OFF_STATS = 18890800;                // 12 KB
    constexpr size_t OFF_BIAS  = 18903088;                // 32 KB
    constexpr size_t OFF_BB    = 18935856;                // 4 B

    unsigned short* xb  = (unsigned short*)(ws + OFF_XB);
    unsigned short* w1t = (unsigned short*)(ws + OFF_W1T);
    unsigned short* w2t = (unsigned short*)(ws + OFF_W2T);
    float* v2    = (float*)(ws + OFF_V2);
    float* bc2   = (float*)(ws + OFF_BC2);
    float* S1    = (float*)(ws + OFF_S1);
    float* S2    = (float*)(ws + OFF_S2);
    float* ncnt  = (float*)(ws + OFF_N);
    float* stats = (float*)(ws + OFF_STATS);
    float* bias  = (float*)(ws + OFF_BIAS);
    float* bbeta = (float*)(ws + OFF_BB);

    hipMemsetAsync(ws + OFF_S1, 0, 4096 + 4096 + 16, stream);

    k_w1t<<<128, 256, 0, stream>>>(W1, w1t);
    k_w2t<<<128, 256, 0, stream>>>(W2, w2t);
    k_v2<<<2048, 256, 0, stream>>>(W2, We, b2, be, log_beta, prior, v2, bc2, bbeta);
    k_stats<<<256, 256, 0, stream>>>(x, mask, lnw, lnb, S1, S2, ncnt, xb);
    k_stats_fin<<<4, 256, 0, stream>>>(S1, S2, ncnt, stats);
    k_bias<<<32, 256, 0, stream>>>(W1, b1, stats, bias);
    k_fused<<<512, 256, 0, stream>>>(xb, w1t, w2t, bias, v2, bc2, bbeta, mask, b2, out);
}

// Round 9
// 360.272 us; speedup vs baseline: 1.3796x; 1.3796x over previous
//
#include <hip/hip_runtime.h>
#include <cmath>

#define B_ 4
#define T_ 8192
#define C_ 256
#define E_ 8
#define M_ (B_*T_)

typedef __bf16 bf16x8 __attribute__((ext_vector_type(8)));
typedef float  f32x4  __attribute__((ext_vector_type(4)));

typedef const __attribute__((address_space(1))) unsigned int* gas_t;
typedef __attribute__((address_space(3))) unsigned int* las_t;

static __device__ __forceinline__ unsigned short f2bf(float f) {
    union { float fv; unsigned u; } v; v.fv = f;
    unsigned r = v.u + 0x7FFFu + ((v.u >> 16) & 1u);
    return (unsigned short)(r >> 16);
}

// Abramowitz-Stegun 7.1.26: |err| <= 1.5e-7
static __device__ __forceinline__ float fast_erf(float x) {
    float ax = fabsf(x);
    float t = __builtin_amdgcn_rcpf(1.0f + 0.3275911f * ax);
    float p = ((((1.061405429f * t - 1.453152027f) * t) + 1.421413741f) * t - 0.284496736f) * t + 0.254829592f;
    float y = 1.0f - p * t * __expf(-ax * ax);
    return copysignf(y, x);
}

static __device__ __forceinline__ float gelu_f(float x) {
    return 0.5f * x * (1.0f + fast_erf(x * 0.7071067811865476f));
}

static __device__ __forceinline__ f32x4 mfma16(bf16x8 a, bf16x8 b, f32x4 c) {
    return __builtin_amdgcn_mfma_f32_16x16x32_bf16(a, b, c, 0, 0, 0);
}

// stage one 16KB weight chunk [256 cols][32 k] bf16 into LDS with 512 threads
// (2 x 16B loads/thread -> vmcnt +2 per stage).
// LDS 16B-slot s holds (col = s>>2, kseg = (s&3) ^ ((col>>1)&3)); read side
// slot = (col<<2) + (khi ^ ((col>>1)&3)) -> 2-way max bank aliasing (free).
// LDS dest linear (global_load_lds constraint); source pre-swizzled.
static __device__ __forceinline__ void stage_swz(const unsigned short* __restrict__ src,
                                                 unsigned short* lds_base, int tid) {
#pragma unroll
    for (int j = 0; j < 2; j++) {
        int s = (j << 9) + tid;
        int col = s >> 2;
        int kseg = (s & 3) ^ ((col >> 1) & 3);
        const unsigned short* gp = src + (col << 8) + (kseg << 3);
        unsigned short* lp = lds_base + (((j << 9) + (tid & ~63)) << 3);
        __builtin_amdgcn_global_load_lds((gas_t)(const void*)gp, (las_t)(void*)lp, 16, 0, 0);
    }
}

// ---------------- prep kernels ----------------

// w1t[e][c][k] = W1[e][k][c], k in [0,256)  (tiled coalesced transpose)
__global__ void k_w1t(const float* __restrict__ W1, unsigned short* __restrict__ w1t) {
    __shared__ float tile[64][65];
    int e = blockIdx.x >> 4, kt = (blockIdx.x >> 2) & 3, ct = blockIdx.x & 3;
    int k0 = kt << 6, c0 = ct << 6;
    const float* src = W1 + ((size_t)e << 18) + ((size_t)k0 << 8) + c0;
    int r = threadIdx.x >> 6, col = threadIdx.x & 63;
#pragma unroll
    for (int i = 0; i < 16; i++)
        tile[r + i * 4][col] = src[(size_t)(r + i * 4) * 256 + col];
    __syncthreads();
    unsigned short* dst = w1t + (e << 16) + (c0 << 8) + k0;
#pragma unroll
    for (int i = 0; i < 16; i++)
        dst[(r + i * 4) * 256 + col] = f2bf(tile[col][r + i * 4]);
}

// w2t[e][f][c] = W2[e][c][f]
__global__ void k_w2t(const float* __restrict__ W2, unsigned short* __restrict__ w2t) {
    __shared__ float tile[64][65];
    int e = blockIdx.x >> 4, ct = (blockIdx.x >> 2) & 3, ft = blockIdx.x & 3;
    int c0 = ct << 6, f0 = ft << 6;
    const float* src = W2 + ((size_t)e << 16) + ((size_t)c0 << 8) + f0;
    int r = threadIdx.x >> 6, col = threadIdx.x & 63;
#pragma unroll
    for (int i = 0; i < 16; i++)
        tile[r + i * 4][col] = src[(size_t)(r + i * 4) * 256 + col];
    __syncthreads();
    unsigned short* dst = w2t + (e << 16) + (f0 << 8) + c0;
#pragma unroll
    for (int i = 0; i < 16; i++)
        dst[(r + i * 4) * 256 + col] = f2bf(tile[col][r + i * 4]);
}

// v2[e][c] = sum_f W2[e,c,f]*We[e,f];
// bc2[e] = -beta*( sum_f b2[e,f]*We[e,f] + be[e] + prior[e] );  bbeta[0] = beta
__global__ void k_v2(const float* __restrict__ W2, const float* __restrict__ We,
                     const float* __restrict__ b2, const float* __restrict__ be,
                     const float* __restrict__ log_beta, const float* __restrict__ prior,
                     float* __restrict__ v2, float* __restrict__ bc2, float* __restrict__ bbeta) {
    __shared__ float sm[4];
    int e = blockIdx.x >> 8, c = blockIdx.x & 255, f = threadIdx.x;
    float wef = We[(e << 8) + f];
    float v = W2[((((e << 8) + c) << 8)) + f] * wef;
#pragma unroll
    for (int m = 32; m >= 1; m >>= 1) v += __shfl_xor(v, m);
    if ((f & 63) == 0) sm[f >> 6] = v;
    __syncthreads();
    if (f == 0) v2[(e << 8) + c] = sm[0] + sm[1] + sm[2] + sm[3];
    if (c == 0) {
        __syncthreads();
        float u = b2[(e << 8) + f] * wef;
#pragma unroll
        for (int m = 32; m >= 1; m >>= 1) u += __shfl_xor(u, m);
        if ((f & 63) == 0) sm[f >> 6] = u;
        __syncthreads();
        if (f == 0) {
            float beta = __expf(log_beta[0]);
            float c2e = sm[0] + sm[1] + sm[2] + sm[3] + be[e];
            bc2[e] = -beta * (c2e + prior[e]);
            if (e == 0) bbeta[0] = beta;
        }
    }
}

// ---------------- LN + masked stats (+ x -> bf16 conversion fused) ----------------

__global__ void k_stats(const float* __restrict__ x, const int* __restrict__ mask,
                        const float* __restrict__ lnw, const float* __restrict__ lnb,
                        float* __restrict__ S1, float* __restrict__ S2, float* __restrict__ ncnt,
                        unsigned short* __restrict__ xb) {
    int b = blockIdx.x >> 6;
    int chunk = blockIdx.x & 63;
    int wid = threadIdx.x >> 6, lane = threadIdx.x & 63;
    int c0 = lane << 2;
    float4 w4 = *reinterpret_cast<const float4*>(lnw + c0);
    float4 b4 = *reinterpret_cast<const float4*>(lnb + c0);
    float a1[4] = {0,0,0,0}, a2[4] = {0,0,0,0};
    int cnt = 0;
    int tbase = chunk * 128;
    for (int r = wid; r < 128; r += 4) {
        int row = b * T_ + tbase + r;
        float4 xv = *reinterpret_cast<const float4*>(x + (size_t)row * C_ + c0);
        ushort4 o;
        o.x = f2bf(xv.x); o.y = f2bf(xv.y); o.z = f2bf(xv.z); o.w = f2bf(xv.w);
        *reinterpret_cast<ushort4*>(xb + (size_t)row * C_ + c0) = o;
        float s1 = xv.x + xv.y + xv.z + xv.w;
        float s2 = xv.x*xv.x + xv.y*xv.y + xv.z*xv.z + xv.w*xv.w;
#pragma unroll
        for (int m = 1; m < 64; m <<= 1) { s1 += __shfl_xor(s1, m); s2 += __shfl_xor(s2, m); }
        if (mask[row]) {
            float mu = s1 * (1.f / C_);
            float var = s2 * (1.f / C_) - mu * mu;
            float rs = rsqrtf(var + 1e-5f);
            float hv;
            hv = (xv.x - mu) * rs * w4.x + b4.x; a1[0] += hv; a2[0] += hv * hv;
            hv = (xv.y - mu) * rs * w4.y + b4.y; a1[1] += hv; a2[1] += hv * hv;
            hv = (xv.z - mu) * rs * w4.z + b4.z; a1[2] += hv; a2[2] += hv * hv;
            hv = (xv.w - mu) * rs * w4.w + b4.w; a1[3] += hv; a2[3] += hv * hv;
            cnt++;
        }
    }
    __shared__ float red[4][256];
    __shared__ int rc[4];
#pragma unroll
    for (int j = 0; j < 4; j++) red[wid][c0 + j] = a1[j];
    if (lane == 0) rc[wid] = cnt;
    __syncthreads();
    int ch = threadIdx.x;
    float s = red[0][ch] + red[1][ch] + red[2][ch] + red[3][ch];
    atomicAdd(&S1[(b << 8) + ch], s);
    if (threadIdx.x == 0) atomicAdd(&ncnt[b], (float)(rc[0] + rc[1] + rc[2] + rc[3]));
    __syncthreads();
#pragma unroll
    for (int j = 0; j < 4; j++) red[wid][c0 + j] = a2[j];
    __syncthreads();
    s = red[0][ch] + red[1][ch] + red[2][ch] + red[3][ch];
    atomicAdd(&S2[(b << 8) + ch], s);
}

__global__ void k_stats_fin(const float* __restrict__ S1, const float* __restrict__ S2,
                            const float* __restrict__ ncnt, float* __restrict__ stats) {
    int b = blockIdx.x, c = threadIdx.x;
    float n = fmaxf(ncnt[b], 1.f);
    float mean = S1[(b << 8) + c] / n;
    float var_b = fmaxf(S2[(b << 8) + c] / n - mean * mean, 0.f);
    float var_u = (n > 1.f) ? (var_b * (n / fmaxf(n - 1.f, 1e-9f))) : var_b;
    float std_u = fmaxf(sqrtf(var_u), 1e-9f);
    stats[b * 768 + 0 * 256 + c] = mean;
    stats[b * 768 + 1 * 256 + c] = std_u;
    stats[b * 768 + 2 * 256 + c] = var_u;
}

__global__ void k_bias(const float* __restrict__ W1, const float* __restrict__ b1,
                       const float* __restrict__ stats, float* __restrict__ bias) {
    int b = blockIdx.x >> 3, e = blockIdx.x & 7, c = threadIdx.x;
    __shared__ float sm[768];
    for (int i = threadIdx.x; i < 768; i += 256) sm[i] = stats[b * 768 + i];
    __syncthreads();
    const float* w = W1 + (size_t)e * 1024 * 256;
    float acc = b1[(e << 8) + c];
#pragma unroll 4
    for (int j = 0; j < 256; j++) {
        acc += sm[j]       * w[(256 + j) * 256 + c];
        acc += sm[256 + j] * w[(512 + j) * 256 + c];
        acc += sm[512 + j] * w[(768 + j) * 256 + c];
    }
    bias[((b << 3) + e) * 256 + c] = acc;
}

// ---------------- fused: GEMM1 + gelu + energy + online softmax + GEMM2 ----------------
// 256 blocks x 512 threads, 128 rows/block, 1 block/CU. 8 waves, each owning
// 16 rows end-to-end (A in regs, per-wave private h1 slice, per-lane online
// softmax) -- the only cross-wave shared resource is the staging buffer.
// Depth-2 counted-vmcnt pipeline: 3 x 16KB buffers; phase p issues stage(p+2),
// then s_waitcnt vmcnt(2) + raw s_barrier -> stage(p+1) stays in flight across
// the barrier (never drains to 0 in the loop). Per-expert global const loads
// are issued BEFORE the stage issue (compiler barrier) so FIFO vmcnt retires
// them without forcing the prefetch to complete.

__global__ __launch_bounds__(512, 2) void k_fused(
    const unsigned short* __restrict__ xb, const unsigned short* __restrict__ w1t,
    const unsigned short* __restrict__ w2t, const float* __restrict__ bias,
    const float* __restrict__ v2, const float* __restrict__ bc2,
    const float* __restrict__ bbeta, const int* __restrict__ mask,
    const float* __restrict__ b2, float* __restrict__ out) {
    __shared__ unsigned short bstage[3][8192];  // 3 x 16KB swizzled weight chunks
    __shared__ unsigned short h1s[8][4096];     // per-wave [16][256] bf16, row-XOR

    int row0 = blockIdx.x << 7;
    int b = row0 >> 13;
    int tid = threadIdx.x;
    int w = tid >> 6, lane = tid & 63;
    int rlo = lane & 15, khi = lane >> 4;
    unsigned short* h1w = h1s[w];
    int wr0 = row0 + (w << 4);                  // wave's first row

    // prologue: per-lane constants + A rows in registers
    float beta = bbeta[0];
    float bc2r[8];
#pragma unroll
    for (int e = 0; e < 8; e++) bc2r[e] = bc2[e];
    int mask4[4];
#pragma unroll
    for (int i = 0; i < 4; i++) mask4[i] = mask[wr0 + (khi << 2) + i];
    const unsigned short* arow = xb + (size_t)(wr0 + rlo) * C_ + (khi << 3);
    bf16x8 areg[8];
#pragma unroll
    for (int kk = 0; kk < 8; kk++) areg[kk] = *reinterpret_cast<const bf16x8*>(arow + (kk << 5));

    f32x4 acc2[16];
#pragma unroll
    for (int n = 0; n < 16; n++)
#pragma unroll
        for (int i = 0; i < 4; i++) acc2[n][i] = 0.f;
    float m_run[4], s_run[4];
#pragma unroll
    for (int i = 0; i < 4; i++) { m_run[i] = -3.0e38f; s_run[i] = 0.f; }

    // stage chunks 0 (w1t e0 k0) and 1 (w1t e0 k1); issued last in prologue
    asm volatile("" ::: "memory");
    stage_swz(w1t, &bstage[0][0], tid);
    stage_swz(w1t + 32, &bstage[1][0], tid);
    asm volatile("s_waitcnt vmcnt(2) lgkmcnt(0)" ::: "memory");
    __builtin_amdgcn_s_barrier();

    int bufc = 0;
    for (int e = 0; e < E_; e++) {
        const float* bre = bias + (((b << 3) + e) << 8);
        f32x4 acc1[16];
        // ========== GEMM1: 8 pipelined phases ==========
#pragma unroll
        for (int g = 0; g < 8; g++) {
            int p = (e << 4) + g;
            if (g == 0) {
#pragma unroll
                for (int n = 0; n < 16; n++) {
                    float bv = bre[(n << 4) + rlo];
#pragma unroll
                    for (int i = 0; i < 4; i++) acc1[n][i] = bv;
                }
                asm volatile("" ::: "memory");   // consts issued before stage
            }
            int p2 = p + 2;
            int bufs = bufc + 2; if (bufs >= 3) bufs -= 3;
            if (p2 < 128) {
                const unsigned short* nsrc = (((p2 >> 3) & 1) ? w2t : w1t) + ((p2 >> 4) << 16) + ((p2 & 7) << 5);
                stage_swz(nsrc, &bstage[bufs][0], tid);
            }
            const unsigned short* bs = &bstage[bufc][0];
            bf16x8 a = areg[g];
#pragma unroll
            for (int n = 0; n < 16; n++) {
                int col = (n << 4) + rlo;
                int slot = (col << 2) + (khi ^ ((col >> 1) & 3));
                bf16x8 bf = *reinterpret_cast<const bf16x8*>(bs + (slot << 3));
                acc1[n] = mfma16(a, bf, acc1[n]);
            }
            if (p2 < 128) asm volatile("s_waitcnt vmcnt(2) lgkmcnt(0)" ::: "memory");
            else          asm volatile("s_waitcnt vmcnt(0) lgkmcnt(0)" ::: "memory");
            __builtin_amdgcn_s_barrier();
            bufc = (bufc == 2) ? 0 : bufc + 1;
        }
        // ========== GEMM2: 8 pipelined phases ==========
        float rr[4], uu[4];
#pragma unroll
        for (int g = 0; g < 8; g++) {
            int p = (e << 4) + 8 + g;
            float v2v[16], b2v[16];
            if (g == 0) {
#pragma unroll
                for (int n = 0; n < 16; n++) {
                    v2v[n] = v2[(e << 8) + (n << 4) + rlo];
                    b2v[n] = b2[(e << 8) + (n << 4) + rlo];
                }
                asm volatile("" ::: "memory");   // consts issued before stage
            }
            int p2 = p + 2;
            int bufs = bufc + 2; if (bufs >= 3) bufs -= 3;
            if (p2 < 128) {
                const unsigned short* nsrc = (((p2 >> 3) & 1) ? w2t : w1t) + ((p2 >> 4) << 16) + ((p2 & 7) << 5);
                stage_swz(nsrc, &bstage[bufs][0], tid);
            }
            if (g == 0) {
                // gelu + energy row-reduce + online softmax (overlaps stage flight)
                float epr[4] = {0, 0, 0, 0};
#pragma unroll
                for (int n = 0; n < 16; n++)
#pragma unroll
                    for (int i = 0; i < 4; i++) {
                        float gl = gelu_f(acc1[n][i]);
                        acc1[n][i] = gl;
                        epr[i] += gl * v2v[n];
                    }
#pragma unroll
                for (int m = 1; m < 16; m <<= 1)
#pragma unroll
                    for (int i = 0; i < 4; i++) epr[i] += __shfl_xor(epr[i], m);
#pragma unroll
                for (int i = 0; i < 4; i++) {
                    float nb = -beta * epr[i] + bc2r[e];
                    float mn = fmaxf(m_run[i], nb);
                    rr[i] = __expf(m_run[i] - mn);
                    uu[i] = __expf(nb - mn);
                    s_run[i] = s_run[i] * rr[i] + uu[i];
                    m_run[i] = mn;
                }
                // unscaled gelu(h1) -> wave-private LDS slice (row-XOR swizzle)
#pragma unroll
                for (int n = 0; n < 16; n++)
#pragma unroll
                    for (int i = 0; i < 4; i++) {
                        int row_l = (khi << 2) + i;
                        int col = (n << 4) + rlo;
                        int byteoff = ((row_l << 9) + (col << 1)) ^ ((row_l & 7) << 4);
                        *reinterpret_cast<unsigned short*>(reinterpret_cast<char*>(h1w) + byteoff)
                            = f2bf(acc1[n][i]);
                    }
                asm volatile("s_waitcnt lgkmcnt(0)" ::: "memory");  // wave-private RAW
#pragma unroll
                for (int n = 0; n < 16; n++)
#pragma unroll
                    for (int i = 0; i < 4; i++) acc1[n][i] = b2v[n];
            }
            // A from wave-private h1, B from staged chunk
            int byteoff = ((rlo << 9) + (g << 6) + (khi << 4)) ^ ((rlo & 7) << 4);
            bf16x8 a2 = *reinterpret_cast<const bf16x8*>(reinterpret_cast<const char*>(h1w) + byteoff);
            const unsigned short* bs = &bstage[bufc][0];
#pragma unroll
            for (int n = 0; n < 16; n++) {
                int col = (n << 4) + rlo;
                int slot = (col << 2) + (khi ^ ((col >> 1) & 3));
                bf16x8 bf = *reinterpret_cast<const bf16x8*>(bs + (slot << 3));
                acc1[n] = mfma16(a2, bf, acc1[n]);
            }
            if (g == 7) {
                // merge: acc2 = acc2*rr + uu*acc1
#pragma unroll
                for (int n = 0; n < 16; n++)
#pragma unroll
                    for (int i = 0; i < 4; i++)
                        acc2[n][i] = acc2[n][i] * rr[i] + uu[i] * acc1[n][i];
            }
            if (p2 < 128) asm volatile("s_waitcnt vmcnt(2) lgkmcnt(0)" ::: "memory");
            else          asm volatile("s_waitcnt vmcnt(0) lgkmcnt(0)" ::: "memory");
            __builtin_amdgcn_s_barrier();
            bufc = (bufc == 2) ? 0 : bufc + 1;
        }
    }
    // ---- epilogue: divide by partition sum, mask ----
    float si[4];
#pragma unroll
    for (int i = 0; i < 4; i++) si[i] = mask4[i] ? (1.0f / s_run[i]) : 0.f;
#pragma unroll
    for (int n = 0; n < 16; n++) {
        int col = (n << 4) + rlo;
#pragma unroll
        for (int i = 0; i < 4; i++)
            out[(size_t)(wr0 + (khi << 2) + i) * C_ + col] = acc2[n][i] * si[i];
    }
}

// ---------------- launch ----------------

extern "C" void kernel_launch(void* const* d_in, const int* in_sizes, int n_in,
                              void* d_out, int out_size, void* d_ws, size_t ws_size,
                              hipStream_t stream) {
    (void)in_sizes; (void)n_in; (void)out_size; (void)ws_size;
    const float* x        = (const float*)d_in[0];
    const int*   mask     = (const int*)d_in[1];
    const float* lnw      = (const float*)d_in[2];
    const float* lnb      = (const float*)d_in[3];
    const float* W1       = (const float*)d_in[4];
    const float* b1       = (const float*)d_in[5];
    const float* W2       = (const float*)d_in[6];
    const float* b2       = (const float*)d_in[7];
    const float* We       = (const float*)d_in[8];
    const float* be       = (const float*)d_in[9];
    const float* log_beta = (const float*)d_in[10];
    const float* prior    = (const float*)d_in[11];
    float* out = (float*)d_out;
    char* ws = (char*)d_ws;

    constexpr size_t OFF_XB    = 0;                       // 16 MB
    constexpr size_t OFF_W1T   = 16777216;                // 1 MB
    constexpr size_t OFF_W2T   = 17825792;                // 1 MB
    constexpr size_t OFF_V2    = 18874368;                // 8 KB
    constexpr size_t OFF_BC2   = 18882560;                // 32 B
    constexpr size_t OFF_S1    = 18882592;                // 4 KB
    constexpr size_t OFF_S2    = 18886688;                // 4 KB
    constexpr size_t OFF_N     = 18890784;                // 16 B
    constexpr size_t OFF_STATS = 18890800;                // 12 KB
    constexpr size_t OFF_BIAS  = 18903088;                // 32 KB
    constexpr size_t OFF_BB    = 18935856;                // 4 B

    unsigned short* xb  = (unsigned short*)(ws + OFF_XB);
    unsigned short* w1t = (unsigned short*)(ws + OFF_W1T);
    unsigned short* w2t = (unsigned short*)(ws + OFF_W2T);
    float* v2    = (float*)(ws + OFF_V2);
    float* bc2   = (float*)(ws + OFF_BC2);
    float* S1    = (float*)(ws + OFF_S1);
    float* S2    = (float*)(ws + OFF_S2);
    float* ncnt  = (float*)(ws + OFF_N);
    float* stats = (float*)(ws + OFF_STATS);
    float* bias  = (float*)(ws + OFF_BIAS);
    float* bbeta = (float*)(ws + OFF_BB);

    hipMemsetAsync(ws + OFF_S1, 0, 4096 + 4096 + 16, stream);

    k_w1t<<<128, 256, 0, stream>>>(W1, w1t);
    k_w2t<<<128, 256, 0, stream>>>(W2, w2t);
    k_v2<<<2048, 256, 0, stream>>>(W2, We, b2, be, log_beta, prior, v2, bc2, bbeta);
    k_stats<<<256, 256, 0, stream>>>(x, mask, lnw, lnb, S1, S2, ncnt, xb);
    k_stats_fin<<<4, 256, 0, stream>>>(S1, S2, ncnt, stats);
    k_bias<<<32, 256, 0, stream>>>(W1, b1, stats, bias);
    k_fused<<<256, 512, 0, stream>>>(xb, w1t, w2t, bias, v2, bc2, bbeta, mask, b2, out);
}

// Round 10
// 317.270 us; speedup vs baseline: 1.5666x; 1.1355x over previous
//
#include <hip/hip_runtime.h>
#include <cmath>

#define B_ 4
#define T_ 8192
#define C_ 256
#define E_ 8
#define M_ (B_*T_)

typedef __bf16 bf16x8 __attribute__((ext_vector_type(8)));
typedef float  f32x4  __attribute__((ext_vector_type(4)));

typedef const __attribute__((address_space(1))) unsigned int* gas_t;
typedef __attribute__((address_space(3))) unsigned int* las_t;

static __device__ __forceinline__ unsigned short f2bf(float f) {
    union { float fv; unsigned u; } v; v.fv = f;
    unsigned r = v.u + 0x7FFFu + ((v.u >> 16) & 1u);
    return (unsigned short)(r >> 16);
}

// Abramowitz-Stegun 7.1.26: |err| <= 1.5e-7
static __device__ __forceinline__ float fast_erf(float x) {
    float ax = fabsf(x);
    float t = __builtin_amdgcn_rcpf(1.0f + 0.3275911f * ax);
    float p = ((((1.061405429f * t - 1.453152027f) * t) + 1.421413741f) * t - 0.284496736f) * t + 0.254829592f;
    float y = 1.0f - p * t * __expf(-ax * ax);
    return copysignf(y, x);
}

static __device__ __forceinline__ float gelu_f(float x) {
    return 0.5f * x * (1.0f + fast_erf(x * 0.7071067811865476f));
}

static __device__ __forceinline__ f32x4 mfma16(bf16x8 a, bf16x8 b, f32x4 c) {
    return __builtin_amdgcn_mfma_f32_16x16x32_bf16(a, b, c, 0, 0, 0);
}

// stage one 16KB weight chunk [256 cols][32 k] bf16 into LDS (256 thr, 4x16B each
// -> vmcnt +4 per stage). LDS 16B-slot s holds (col=s>>2, kseg=(s&3)^((col>>1)&3));
// read slot = (col<<2) + (khi ^ ((col>>1)&3)) -> 2-way max bank aliasing (free,
// verified round 9: 17.3M -> 0.52M conflicts). LDS dest linear; src pre-swizzled.
static __device__ __forceinline__ void stage_swz(const unsigned short* __restrict__ src,
                                                 unsigned short* lds_base, int tid) {
#pragma unroll
    for (int i = 0; i < 4; i++) {
        int s = i * 256 + tid;
        int col = s >> 2;
        int kseg = (s & 3) ^ ((col >> 1) & 3);
        const unsigned short* gp = src + (col << 8) + (kseg << 3);
        unsigned short* lp = lds_base + ((i * 256 + (tid & ~63)) << 3);
        __builtin_amdgcn_global_load_lds((gas_t)(const void*)gp, (las_t)(void*)lp, 16, 0, 0);
    }
}

// ---------------- prep kernels ----------------

__global__ void k_w1t(const float* __restrict__ W1, unsigned short* __restrict__ w1t) {
    __shared__ float tile[64][65];
    int e = blockIdx.x >> 4, kt = (blockIdx.x >> 2) & 3, ct = blockIdx.x & 3;
    int k0 = kt << 6, c0 = ct << 6;
    const float* src = W1 + ((size_t)e << 18) + ((size_t)k0 << 8) + c0;
    int r = threadIdx.x >> 6, col = threadIdx.x & 63;
#pragma unroll
    for (int i = 0; i < 16; i++)
        tile[r + i * 4][col] = src[(size_t)(r + i * 4) * 256 + col];
    __syncthreads();
    unsigned short* dst = w1t + (e << 16) + (c0 << 8) + k0;
#pragma unroll
    for (int i = 0; i < 16; i++)
        dst[(r + i * 4) * 256 + col] = f2bf(tile[col][r + i * 4]);
}

__global__ void k_w2t(const float* __restrict__ W2, unsigned short* __restrict__ w2t) {
    __shared__ float tile[64][65];
    int e = blockIdx.x >> 4, ct = (blockIdx.x >> 2) & 3, ft = blockIdx.x & 3;
    int c0 = ct << 6, f0 = ft << 6;
    const float* src = W2 + ((size_t)e << 16) + ((size_t)c0 << 8) + f0;
    int r = threadIdx.x >> 6, col = threadIdx.x & 63;
#pragma unroll
    for (int i = 0; i < 16; i++)
        tile[r + i * 4][col] = src[(size_t)(r + i * 4) * 256 + col];
    __syncthreads();
    unsigned short* dst = w2t + (e << 16) + (f0 << 8) + c0;
#pragma unroll
    for (int i = 0; i < 16; i++)
        dst[(r + i * 4) * 256 + col] = f2bf(tile[col][r + i * 4]);
}

// v2[e][c] = sum_f W2[e,c,f]*We[e,f];
// bc2[e] = -beta*( sum_f b2[e,f]*We[e,f] + be[e] + prior[e] );  bbeta[0] = beta
__global__ void k_v2(const float* __restrict__ W2, const float* __restrict__ We,
                     const float* __restrict__ b2, const float* __restrict__ be,
                     const float* __restrict__ log_beta, const float* __restrict__ prior,
                     float* __restrict__ v2, float* __restrict__ bc2, float* __restrict__ bbeta) {
    __shared__ float sm[4];
    int e = blockIdx.x >> 8, c = blockIdx.x & 255, f = threadIdx.x;
    float wef = We[(e << 8) + f];
    float v = W2[((((e << 8) + c) << 8)) + f] * wef;
#pragma unroll
    for (int m = 32; m >= 1; m >>= 1) v += __shfl_xor(v, m);
    if ((f & 63) == 0) sm[f >> 6] = v;
    __syncthreads();
    if (f == 0) v2[(e << 8) + c] = sm[0] + sm[1] + sm[2] + sm[3];
    if (c == 0) {
        __syncthreads();
        float u = b2[(e << 8) + f] * wef;
#pragma unroll
        for (int m = 32; m >= 1; m >>= 1) u += __shfl_xor(u, m);
        if ((f & 63) == 0) sm[f >> 6] = u;
        __syncthreads();
        if (f == 0) {
            float beta = __expf(log_beta[0]);
            float c2e = sm[0] + sm[1] + sm[2] + sm[3] + be[e];
            bc2[e] = -beta * (c2e + prior[e]);
            if (e == 0) bbeta[0] = beta;
        }
    }
}

__global__ void k_stats(const float* __restrict__ x, const int* __restrict__ mask,
                        const float* __restrict__ lnw, const float* __restrict__ lnb,
                        float* __restrict__ S1, float* __restrict__ S2, float* __restrict__ ncnt,
                        unsigned short* __restrict__ xb) {
    int b = blockIdx.x >> 6;
    int chunk = blockIdx.x & 63;
    int wid = threadIdx.x >> 6, lane = threadIdx.x & 63;
    int c0 = lane << 2;
    float4 w4 = *reinterpret_cast<const float4*>(lnw + c0);
    float4 b4 = *reinterpret_cast<const float4*>(lnb + c0);
    float a1[4] = {0,0,0,0}, a2[4] = {0,0,0,0};
    int cnt = 0;
    int tbase = chunk * 128;
    for (int r = wid; r < 128; r += 4) {
        int row = b * T_ + tbase + r;
        float4 xv = *reinterpret_cast<const float4*>(x + (size_t)row * C_ + c0);
        ushort4 o;
        o.x = f2bf(xv.x); o.y = f2bf(xv.y); o.z = f2bf(xv.z); o.w = f2bf(xv.w);
        *reinterpret_cast<ushort4*>(xb + (size_t)row * C_ + c0) = o;
        float s1 = xv.x + xv.y + xv.z + xv.w;
        float s2 = xv.x*xv.x + xv.y*xv.y + xv.z*xv.z + xv.w*xv.w;
#pragma unroll
        for (int m = 1; m < 64; m <<= 1) { s1 += __shfl_xor(s1, m); s2 += __shfl_xor(s2, m); }
        if (mask[row]) {
            float mu = s1 * (1.f / C_);
            float var = s2 * (1.f / C_) - mu * mu;
            float rs = rsqrtf(var + 1e-5f);
            float hv;
            hv = (xv.x - mu) * rs * w4.x + b4.x; a1[0] += hv; a2[0] += hv * hv;
            hv = (xv.y - mu) * rs * w4.y + b4.y; a1[1] += hv; a2[1] += hv * hv;
            hv = (xv.z - mu) * rs * w4.z + b4.z; a1[2] += hv; a2[2] += hv * hv;
            hv = (xv.w - mu) * rs * w4.w + b4.w; a1[3] += hv; a2[3] += hv * hv;
            cnt++;
        }
    }
    __shared__ float red[4][256];
    __shared__ int rc[4];
#pragma unroll
    for (int j = 0; j < 4; j++) red[wid][c0 + j] = a1[j];
    if (lane == 0) rc[wid] = cnt;
    __syncthreads();
    int ch = threadIdx.x;
    float s = red[0][ch] + red[1][ch] + red[2][ch] + red[3][ch];
    atomicAdd(&S1[(b << 8) + ch], s);
    if (threadIdx.x == 0) atomicAdd(&ncnt[b], (float)(rc[0] + rc[1] + rc[2] + rc[3]));
    __syncthreads();
#pragma unroll
    for (int j = 0; j < 4; j++) red[wid][c0 + j] = a2[j];
    __syncthreads();
    s = red[0][ch] + red[1][ch] + red[2][ch] + red[3][ch];
    atomicAdd(&S2[(b << 8) + ch], s);
}

__global__ void k_stats_fin(const float* __restrict__ S1, const float* __restrict__ S2,
                            const float* __restrict__ ncnt, float* __restrict__ stats) {
    int b = blockIdx.x, c = threadIdx.x;
    float n = fmaxf(ncnt[b], 1.f);
    float mean = S1[(b << 8) + c] / n;
    float var_b = fmaxf(S2[(b << 8) + c] / n - mean * mean, 0.f);
    float var_u = (n > 1.f) ? (var_b * (n / fmaxf(n - 1.f, 1e-9f))) : var_b;
    float std_u = fmaxf(sqrtf(var_u), 1e-9f);
    stats[b * 768 + 0 * 256 + c] = mean;
    stats[b * 768 + 1 * 256 + c] = std_u;
    stats[b * 768 + 2 * 256 + c] = var_u;
}

__global__ void k_bias(const float* __restrict__ W1, const float* __restrict__ b1,
                       const float* __restrict__ stats, float* __restrict__ bias) {
    int b = blockIdx.x >> 3, e = blockIdx.x & 7, c = threadIdx.x;
    __shared__ float sm[768];
    for (int i = threadIdx.x; i < 768; i += 256) sm[i] = stats[b * 768 + i];
    __syncthreads();
    const float* w = W1 + (size_t)e * 1024 * 256;
    float acc = b1[(e << 8) + c];
#pragma unroll 4
    for (int j = 0; j < 256; j++) {
        acc += sm[j]       * w[(256 + j) * 256 + c];
        acc += sm[256 + j] * w[(512 + j) * 256 + c];
        acc += sm[512 + j] * w[(768 + j) * 256 + c];
    }
    bias[((b << 3) + e) * 256 + c] = acc;
}

// ---------------- fused: GEMM1 + gelu + energy + online softmax + GEMM2 ----------------
// 512 blocks x 256 thr (2 blocks/CU), 64 rows/block, 4 waves x 16 rows (A in regs,
// wave-private h1 slice, per-lane online softmax). Depth-2 counted-vmcnt pipeline:
// 3 x 16KB staging buffers; phase p issues stage(p+2) then s_waitcnt vmcnt(4) +
// raw s_barrier -> stage(p+1) stays in flight across the barrier. Per-expert
// consts issued at g=6/7 (FIFO-retired by the counted wait, minimal liveness).
// uu folded into h1 write + GEMM2 acc init (merge = 1 FMA). LDS = 48+32 = 80KB.

__global__ __launch_bounds__(256, 2) void k_fused(
    const unsigned short* __restrict__ xb, const unsigned short* __restrict__ w1t,
    const unsigned short* __restrict__ w2t, const float* __restrict__ bias,
    const float* __restrict__ v2, const float* __restrict__ bc2,
    const float* __restrict__ bbeta, const int* __restrict__ mask,
    const float* __restrict__ b2, float* __restrict__ out) {
    __shared__ unsigned short bstage[3][8192];  // 3 x 16KB swizzled weight chunks
    __shared__ unsigned short h1_s[4][4096];    // per-wave [16][256] bf16, row-XOR

    int row0 = blockIdx.x << 6;
    int b = row0 >> 13;
    int tid = threadIdx.x;
    int wid = tid >> 6, lane = tid & 63;
    int rlo = lane & 15, khi = lane >> 4;
    unsigned short* h1w = h1_s[wid];

    float beta = bbeta[0];

    // A rows in registers (16 rows/wave), reused across all experts
    const unsigned short* arow = xb + (size_t)(row0 + (wid << 4) + rlo) * C_ + (khi << 3);
    bf16x8 areg[8];
#pragma unroll
    for (int kk = 0; kk < 8; kk++) areg[kk] = *reinterpret_cast<const bf16x8*>(arow + (kk << 5));

    f32x4 acc2[16];
#pragma unroll
    for (int n = 0; n < 16; n++)
#pragma unroll
        for (int i = 0; i < 4; i++) acc2[n][i] = 0.f;
    float m_run[4], s_run[4];
#pragma unroll
    for (int i = 0; i < 4; i++) { m_run[i] = -3.0e38f; s_run[i] = 0.f; }

    // prologue: stage chunks 0,1 (issued after areg loads -> FIFO retires areg first)
    asm volatile("" ::: "memory");
    stage_swz(w1t, &bstage[0][0], tid);
    stage_swz(w1t + 32, &bstage[1][0], tid);
    asm volatile("s_waitcnt vmcnt(4) lgkmcnt(0)" ::: "memory");
    __builtin_amdgcn_s_barrier();

    int bufc = 0;
    for (int e = 0; e < E_; e++) {
        f32x4 acc1[16];
        float bv[16], v2v[16], b2v[16];
        float rr[4], uu[4];
        float bce = 0.f;
#pragma unroll
        for (int g = 0; g < 16; g++) {
            int p = (e << 4) + g;
            if (g == 0) {
#pragma unroll
                for (int n = 0; n < 16; n++)
#pragma unroll
                    for (int i = 0; i < 4; i++) acc1[n][i] = 0.f;
            }
            if (g == 6) {
                // issue bias/v2 loads; FIFO-retired by this phase's vmcnt(4)
                const float* bre = bias + (((b << 3) + e) << 8);
#pragma unroll
                for (int n = 0; n < 16; n++) {
                    bv[n]  = bre[(n << 4) + rlo];
                    v2v[n] = v2[(e << 8) + (n << 4) + rlo];
                }
                bce = bc2[e];
                asm volatile("" ::: "memory");
            }
            if (g == 7) {
#pragma unroll
                for (int n = 0; n < 16; n++) b2v[n] = b2[(e << 8) + (n << 4) + rlo];
                asm volatile("" ::: "memory");
            }
            // stage chunk p+2 into the free buffer
            int p2 = p + 2;
            if (p2 < 128) {
                const unsigned short* nsrc = (((p2 >> 3) & 1) ? w2t : w1t)
                                             + ((p2 >> 4) << 16) + ((p2 & 7) << 5);
                int bufs = bufc + 2; if (bufs >= 3) bufs -= 3;
                stage_swz(nsrc, &bstage[bufs][0], tid);
            }
            if (g == 8) {
                // GEMM2 acc init = uu*b2 (uu folded)
#pragma unroll
                for (int n = 0; n < 16; n++)
#pragma unroll
                    for (int i = 0; i < 4; i++) acc1[n][i] = uu[i] * b2v[n];
            }
            const unsigned short* bs = &bstage[bufc][0];
            bf16x8 a;
            if (g < 8) {
                a = areg[g];
            } else {
                int byteoff = ((rlo << 9) + ((g - 8) << 6) + (khi << 4)) ^ ((rlo & 7) << 4);
                a = *reinterpret_cast<const bf16x8*>(reinterpret_cast<const char*>(h1w) + byteoff);
            }
            __builtin_amdgcn_s_setprio(1);
#pragma unroll
            for (int n = 0; n < 16; n++) {
                int col = (n << 4) + rlo;
                int slot = (col << 2) + (khi ^ ((col >> 1) & 3));
                bf16x8 bf = *reinterpret_cast<const bf16x8*>(bs + (slot << 3));
                acc1[n] = mfma16(a, bf, acc1[n]);
            }
            __builtin_amdgcn_s_setprio(0);
            if (g == 7) {
                // bias add + gelu + energy row-reduce + online softmax + scaled h1
                float epr[4] = {0, 0, 0, 0};
#pragma unroll
                for (int n = 0; n < 16; n++)
#pragma unroll
                    for (int i = 0; i < 4; i++) {
                        float gl = gelu_f(acc1[n][i] + bv[n]);
                        acc1[n][i] = gl;
                        epr[i] += gl * v2v[n];
                    }
#pragma unroll
                for (int m = 1; m < 16; m <<= 1)
#pragma unroll
                    for (int i = 0; i < 4; i++) epr[i] += __shfl_xor(epr[i], m);
#pragma unroll
                for (int i = 0; i < 4; i++) {
                    float nb = -beta * epr[i] + bce;
                    float mn = fmaxf(m_run[i], nb);
                    rr[i] = __expf(m_run[i] - mn);
                    uu[i] = __expf(nb - mn);
                    s_run[i] = s_run[i] * rr[i] + uu[i];
                    m_run[i] = mn;
                }
#pragma unroll
                for (int n = 0; n < 16; n++)
#pragma unroll
                    for (int i = 0; i < 4; i++) {
                        int row_l = (khi << 2) + i;
                        int col = (n << 4) + rlo;
                        int byteoff = ((row_l << 9) + (col << 1)) ^ ((row_l & 7) << 4);
                        *reinterpret_cast<unsigned short*>(reinterpret_cast<char*>(h1w) + byteoff)
                            = f2bf(acc1[n][i] * uu[i]);
                    }
            }
            if (g == 15) {
                // merge: acc2 = acc2*rr + acc1 (uu already folded)
#pragma unroll
                for (int n = 0; n < 16; n++)
#pragma unroll
                    for (int i = 0; i < 4; i++)
                        acc2[n][i] = acc2[n][i] * rr[i] + acc1[n][i];
            }
            if (p2 < 128) asm volatile("s_waitcnt vmcnt(4) lgkmcnt(0)" ::: "memory");
            else          asm volatile("s_waitcnt vmcnt(0) lgkmcnt(0)" ::: "memory");
            __builtin_amdgcn_s_barrier();
            bufc = (bufc == 2) ? 0 : bufc + 1;
        }
    }
    // ---- epilogue: divide by partition sum, mask ----
    float si[4];
#pragma unroll
    for (int i = 0; i < 4; i++) {
        int mreg = mask[row0 + (wid << 4) + (khi << 2) + i];
        si[i] = mreg ? (1.0f / s_run[i]) : 0.f;
    }
#pragma unroll
    for (int n = 0; n < 16; n++) {
        int col = (n << 4) + rlo;
#pragma unroll
        for (int i = 0; i < 4; i++)
            out[(size_t)(row0 + (wid << 4) + (khi << 2) + i) * C_ + col] = acc2[n][i] * si[i];
    }
}

// ---------------- launch ----------------

extern "C" void kernel_launch(void* const* d_in, const int* in_sizes, int n_in,
                              void* d_out, int out_size, void* d_ws, size_t ws_size,
                              hipStream_t stream) {
    (void)in_sizes; (void)n_in; (void)out_size; (void)ws_size;
    const float* x        = (const float*)d_in[0];
    const int*   mask     = (const int*)d_in[1];
    const float* lnw      = (const float*)d_in[2];
    const float* lnb      = (const float*)d_in[3];
    const float* W1       = (const float*)d_in[4];
    const float* b1       = (const float*)d_in[5];
    const float* W2       = (const float*)d_in[6];
    const float* b2       = (const float*)d_in[7];
    const float* We       = (const float*)d_in[8];
    const float* be       = (const float*)d_in[9];
    const float* log_beta = (const float*)d_in[10];
    const float* prior    = (const float*)d_in[11];
    float* out = (float*)d_out;
    char* ws = (char*)d_ws;

    constexpr size_t OFF_XB    = 0;                       // 16 MB
    constexpr size_t OFF_W1T   = 16777216;                // 1 MB
    constexpr size_t OFF_W2T   = 17825792;                // 1 MB
    constexpr size_t OFF_V2    = 18874368;                // 8 KB
    constexpr size_t OFF_BC2   = 18882560;                // 32 B
    constexpr size_t OFF_S1    = 18882592;                // 4 KB
    constexpr size_t OFF_S2    = 18886688;                // 4 KB
    constexpr size_t OFF_N     = 18890784;                // 16 B
    constexpr size_t OFF_STATS = 18890800;                // 12 KB
    constexpr size_t OFF_BIAS  = 18903088;                // 32 KB
    constexpr size_t OFF_BB    = 18935856;                // 4 B

    unsigned short* xb  = (unsigned short*)(ws + OFF_XB);
    unsigned short* w1t = (unsigned short*)(ws + OFF_W1T);
    unsigned short* w2t = (unsigned short*)(ws + OFF_W2T);
    float* v2    = (float*)(ws + OFF_V2);
    float* bc2   = (float*)(ws + OFF_BC2);
    float* S1    = (float*)(ws + OFF_S1);
    float* S2    = (float*)(ws + OFF_S2);
    float* ncnt  = (float*)(ws + OFF_N);
    float* stats = (float*)(ws + OFF_STATS);
    float* bias  = (float*)(ws + OFF_BIAS);
    float* bbeta = (float*)(ws + OFF_BB);

    hipMemsetAsync(ws + OFF_S1, 0, 4096 + 4096 + 16, stream);

    k_w1t<<<128, 256, 0, stream>>>(W1, w1t);
    k_w2t<<<128, 256, 0, stream>>>(W2, w2t);
    k_v2<<<2048, 256, 0, stream>>>(W2, We, b2, be, log_beta, prior, v2, bc2, bbeta);
    k_stats<<<256, 256, 0, stream>>>(x, mask, lnw, lnb, S1, S2, ncnt, xb);
    k_stats_fin<<<4, 256, 0, stream>>>(S1, S2, ncnt, stats);
    k_bias<<<32, 256, 0, stream>>>(W1, b1, stats, bias);
    k_fused<<<512, 256, 0, stream>>>(xb, w1t, w2t, bias, v2, bc2, bbeta, mask, b2, out);
}